// Round 15
// baseline (584.490 us; speedup 1.0000x reference)
//
#include <hip/hip_runtime.h>
#include <hip/hip_bf16.h>

#define FRAMES 512
#define BATCH 2048
#define IN_DIM 84
#define HIDDEN 300
#define OUT_DIM 10

#define MT 16            // batch rows per workgroup
#define HROW 512         // bytes per h row (i8 data 0..319, swizzle pad)
#define BUFB 8192        // bytes per buffer (h region only; x never touches LDS)
#define KFH 5            // i8 h-fragments (K=64 each: k 0..319, 300 real)
#define NT 3             // tiles per wave: t = wv, wv+8, wv+16

#define L2E2 2.88539008177792681f   // 2*log2(e), folded into Wi and qs

typedef __attribute__((ext_vector_type(8))) short s8v;
typedef __attribute__((ext_vector_type(4))) float f4v;
typedef __attribute__((ext_vector_type(4))) int   i4v;

__device__ __forceinline__ short f2b(float x) {
    __hip_bfloat16 h = __float2bfloat16(x);
    return *reinterpret_cast<short*>(&h);
}
__device__ __forceinline__ void lgkm_barrier() {   // no vmcnt drain at barrier
    asm volatile("s_waitcnt lgkmcnt(0)" ::: "memory");
    __builtin_amdgcn_s_barrier();
}
// 8 floats -> 8 bf16 via 4 hardware pack-converts (no builtin on gfx950)
__device__ __forceinline__ s8v cvtpk8(float4 a, float4 b) {
    unsigned u0, u1, u2, u3;
    asm("v_cvt_pk_bf16_f32 %0, %1, %2" : "=v"(u0) : "v"(a.x), "v"(a.y));
    asm("v_cvt_pk_bf16_f32 %0, %1, %2" : "=v"(u1) : "v"(a.z), "v"(a.w));
    asm("v_cvt_pk_bf16_f32 %0, %1, %2" : "=v"(u2) : "v"(b.x), "v"(b.y));
    asm("v_cvt_pk_bf16_f32 %0, %1, %2" : "=v"(u3) : "v"(b.z), "v"(b.w));
    i4v t = (i4v){(int)u0, (int)u1, (int)u2, (int)u3};
    return *(s8v*)&t;
}

// Swapped-operand step:  pre[n][b] = qs*(i8dot: Wh_q . h_q) + (bf16: (c*Wi) . x)
//   h part from LDS (5 x b128/wave); x part's B-fragments loaded DIRECTLY from
//   global per wave (6 per-lane-constant-offset float4, L1-resident slab) and
//   pack-converted at step end for the next step -> x never touches LDS.
//   Clamped offsets (k>=84) read finite garbage that meets zero weights.
//   tanh+quant tail fused (TAIL); h' write = ONE ds_write_b32 per tile.

#define MFI(T, K, ACC) ACC = __builtin_amdgcn_mfma_i32_16x16x64_i8(wq[T][K], bh[K], ACC, 0, 0, 0)
#define TAIL(AI, AF, IDX) do { unsigned b_[4];                                  \
        _Pragma("unroll")                                                       \
        for (int r_ = 0; r_ < 4; ++r_) {                                        \
            float z2_ = fmaf(qs2885, (float)AI[r_], AF[r_]);                    \
            float ex_ = __builtin_amdgcn_exp2f(z2_);                            \
            b_[r_] = __float_as_uint(                                           \
                fmaf(-254.f, __builtin_amdgcn_rcpf(ex_ + 1.f), 12583039.f));    \
        }                                                                       \
        unsigned t0_ = __builtin_amdgcn_perm(b_[1], b_[0], 0x00000400u);        \
        unsigned t1_ = __builtin_amdgcn_perm(b_[3], b_[2], 0x00000400u);        \
        unsigned pk_ = __builtin_amdgcn_perm(t1_, t0_, 0x05040100u);            \
        *(unsigned*)&ldsb[IDX] = pk_; } while (0)

__global__ __launch_bounds__(512, 2)
void rnn_kernel(const float* __restrict__ x, const float* __restrict__ h0,
                const float* __restrict__ Wi, const float* __restrict__ Wh,
                const float* __restrict__ Wo, float* __restrict__ out)
{
    __shared__ __align__(16) char ldsb[2 * BUFB];
    __shared__ float redbuf[8];
    const int tid  = threadIdx.x;
    const int lane = tid & 63;
    const int wv   = tid >> 6;          // wave 0..7
    const int l15  = lane & 15;
    const int lkhi = lane >> 4;
    const int b0   = blockIdx.x * MT;
    const bool w3  = (wv < 3);

    // ---- deterministic global max|Wh| (identical in every WG) ----
    float m = 0.f;
    for (int i = tid; i < HIDDEN * HIDDEN; i += 512)
        m = fmaxf(m, fabsf(Wh[i]));
#pragma unroll
    for (int o = 32; o; o >>= 1) m = fmaxf(m, __shfl_xor(m, o));
    if (lane == 0) redbuf[wv] = m;
    __syncthreads();
    float gm = 0.f;
#pragma unroll
    for (int i = 0; i < 8; ++i) gm = fmaxf(gm, redbuf[i]);
    const float inv_sw = 127.f / gm;                    // Wh -> q
    const float qs2885 = (gm / (127.f * 127.f)) * L2E2; // dequant * 2log2e fused

    // ---- weight-stationary fragments: i8 Wh + bf16 (L2E2 * Wi) ----
    i4v wq[NT][KFH];
    s8v wx0[NT], wx1[NT], wx2[NT];
#pragma unroll
    for (int i = 0; i < NT; ++i) {
        const int n = (wv + 8 * i) * 16 + l15;
#pragma unroll
        for (int kf = 0; kf < KFH; ++kf) {
            int dw0 = 0, dw1 = 0, dw2 = 0, dw3 = 0;
#pragma unroll
            for (int j = 0; j < 16; ++j) {
                int k = kf * 64 + lkhi * 16 + j;
                float f = (n < HIDDEN && k < HIDDEN) ? Wh[n * HIDDEN + k] : 0.f;
                int q = (int)rintf(f * inv_sw) & 255;
                if ((j >> 2) == 0) dw0 |= q << ((j & 3) * 8);
                else if ((j >> 2) == 1) dw1 |= q << ((j & 3) * 8);
                else if ((j >> 2) == 2) dw2 |= q << ((j & 3) * 8);
                else dw3 |= q << ((j & 3) * 8);
            }
            wq[i][kf] = (i4v){dw0, dw1, dw2, dw3};
        }
#pragma unroll
        for (int f = 0; f < 3; ++f) {
            s8v v;
#pragma unroll
            for (int j = 0; j < 8; ++j) {
                int k = f * 32 + lkhi * 8 + j;
                v[j] = f2b((n < HIDDEN && k < IN_DIM) ? L2E2 * Wi[n * IN_DIM + k] : 0.f);
            }
            if (f == 0) wx0[i] = v; else if (f == 1) wx1[i] = v; else wx2[i] = v;
        }
    }

    // ---- zero both h buffers (pads must be 0) ----
    {
        i4v z = (i4v){0, 0, 0, 0};
        for (int i = tid; i < 2 * BUFB / 16; i += 512)
            ((i4v*)ldsb)[i] = z;
    }
    __syncthreads();

    // ---- h0 (quantized) -> buf0 ----
    for (int i = tid; i < MT * HIDDEN; i += 512) {
        int r = i / HIDDEN, c = i % HIDDEN;
        float h = h0[(size_t)(b0 + r) * HIDDEN + c];
        ldsb[r * HROW + ((r & 7) << 4) + c] =
            (char)(__float_as_uint(fmaf(h, 127.f, 12582912.f)) & 255u);
    }

    // ---- per-lane constant bases ----
    const int hrd = l15 * HROW + ((l15 & 7) << 4) + lkhi * 16;   // + kf*64
    const int hwr = l15 * HROW + ((l15 & 7) << 4) + lkhi * 4;    // + t*16
    const f4v zero4 = (f4v){0.f, 0.f, 0.f, 0.f};
    const i4v zeroi = (i4v){0, 0, 0, 0};

    // x row pointer + per-lane-constant float offsets (clamped where k>=84;
    // clamped elems meet zero weights, finite*0 = 0)
    const float* xp = x + (size_t)(b0 + l15) * IN_DIM;
    const int o00 = lkhi * 8,      o01 = lkhi * 8 + 4;
    const int o10 = 32 + lkhi * 8, o11 = 36 + lkhi * 8;
    const int o20 = (lkhi < 3) ? 64 + lkhi * 8 : 0;
    const int o21 = (lkhi < 2) ? 68 + lkhi * 8 : 0;

    // ---- frame-0 x prefetch -> bx ----
    float4 xf0, xf1, xf2, xf3, xf4, xf5;
    xf0 = *(const float4*)(xp + o00); xf1 = *(const float4*)(xp + o01);
    xf2 = *(const float4*)(xp + o10); xf3 = *(const float4*)(xp + o11);
    xf4 = *(const float4*)(xp + o20); xf5 = *(const float4*)(xp + o21);
    s8v bx0 = cvtpk8(xf0, xf1), bx1 = cvtpk8(xf2, xf3), bx2 = cvtpk8(xf4, xf5);
    __syncthreads();

    // STEP: LOADF -> issue loads for frame SF+1 at start, convert at end
#define STEP(PH, SF, LOADF)                                                     \
    {                                                                           \
        if (LOADF) {                                                            \
            const float* r_ = xp + (size_t)((SF) + 1) * (BATCH * IN_DIM);       \
            xf0 = *(const float4*)(r_ + o00); xf1 = *(const float4*)(r_ + o01); \
            xf2 = *(const float4*)(r_ + o10); xf3 = *(const float4*)(r_ + o11); \
            xf4 = *(const float4*)(r_ + o20); xf5 = *(const float4*)(r_ + o21); \
        }                                                                       \
        i4v bh[KFH];                                                            \
        _Pragma("unroll")                                                       \
        for (int kf = 0; kf < KFH; ++kf)                                        \
            bh[kf] = *(const i4v*)&ldsb[(PH) * BUFB + hrd + kf * 64];           \
        __builtin_amdgcn_s_setprio(1);                                          \
        if (w3) {                                                               \
            i4v a0i = __builtin_amdgcn_mfma_i32_16x16x64_i8(wq[0][0], bh[0], zeroi, 0, 0, 0); \
            i4v a1i = __builtin_amdgcn_mfma_i32_16x16x64_i8(wq[1][0], bh[0], zeroi, 0, 0, 0); \
            i4v a2i = __builtin_amdgcn_mfma_i32_16x16x64_i8(wq[2][0], bh[0], zeroi, 0, 0, 0); \
            _Pragma("unroll")                                                   \
            for (int kf = 1; kf < KFH; ++kf) {                                  \
                MFI(0, kf, a0i); MFI(1, kf, a1i); MFI(2, kf, a2i);              \
            }                                                                   \
            f4v a0f = __builtin_amdgcn_mfma_f32_16x16x32_bf16(wx0[0], bx0, zero4, 0, 0, 0); \
            f4v a1f = __builtin_amdgcn_mfma_f32_16x16x32_bf16(wx0[1], bx0, zero4, 0, 0, 0); \
            f4v a2f = __builtin_amdgcn_mfma_f32_16x16x32_bf16(wx0[2], bx0, zero4, 0, 0, 0); \
            a0f = __builtin_amdgcn_mfma_f32_16x16x32_bf16(wx1[0], bx1, a0f, 0, 0, 0); \
            a1f = __builtin_amdgcn_mfma_f32_16x16x32_bf16(wx1[1], bx1, a1f, 0, 0, 0); \
            a2f = __builtin_amdgcn_mfma_f32_16x16x32_bf16(wx1[2], bx1, a2f, 0, 0, 0); \
            a0f = __builtin_amdgcn_mfma_f32_16x16x32_bf16(wx2[0], bx2, a0f, 0, 0, 0); \
            a1f = __builtin_amdgcn_mfma_f32_16x16x32_bf16(wx2[1], bx2, a1f, 0, 0, 0); \
            a2f = __builtin_amdgcn_mfma_f32_16x16x32_bf16(wx2[2], bx2, a2f, 0, 0, 0); \
            __builtin_amdgcn_s_setprio(0);                                      \
            TAIL(a0i, a0f, ((PH) ^ 1) * BUFB + hwr + (wv) * 16);                \
            TAIL(a1i, a1f, ((PH) ^ 1) * BUFB + hwr + (wv + 8) * 16);            \
            TAIL(a2i, a2f, ((PH) ^ 1) * BUFB + hwr + (wv + 16) * 16);           \
        } else {                                                                \
            i4v a0i = __builtin_amdgcn_mfma_i32_16x16x64_i8(wq[0][0], bh[0], zeroi, 0, 0, 0); \
            i4v a1i = __builtin_amdgcn_mfma_i32_16x16x64_i8(wq[1][0], bh[0], zeroi, 0, 0, 0); \
            _Pragma("unroll")                                                   \
            for (int kf = 1; kf < KFH; ++kf) {                                  \
                MFI(0, kf, a0i); MFI(1, kf, a1i);                               \
            }                                                                   \
            f4v a0f = __builtin_amdgcn_mfma_f32_16x16x32_bf16(wx0[0], bx0, zero4, 0, 0, 0); \
            f4v a1f = __builtin_amdgcn_mfma_f32_16x16x32_bf16(wx0[1], bx0, zero4, 0, 0, 0); \
            a0f = __builtin_amdgcn_mfma_f32_16x16x32_bf16(wx1[0], bx1, a0f, 0, 0, 0); \
            a1f = __builtin_amdgcn_mfma_f32_16x16x32_bf16(wx1[1], bx1, a1f, 0, 0, 0); \
            a0f = __builtin_amdgcn_mfma_f32_16x16x32_bf16(wx2[0], bx2, a0f, 0, 0, 0); \
            a1f = __builtin_amdgcn_mfma_f32_16x16x32_bf16(wx2[1], bx2, a1f, 0, 0, 0); \
            __builtin_amdgcn_s_setprio(0);                                      \
            TAIL(a0i, a0f, ((PH) ^ 1) * BUFB + hwr + (wv) * 16);                \
            TAIL(a1i, a1f, ((PH) ^ 1) * BUFB + hwr + (wv + 8) * 16);            \
        }                                                                       \
        if (LOADF) {   /* convert frame SF+1 (landed during compute) */         \
            bx0 = cvtpk8(xf0, xf1); bx1 = cvtpk8(xf2, xf3); bx2 = cvtpk8(xf4, xf5); \
        }                                                                       \
        lgkm_barrier();                                                         \
    }

    for (int s = 0; s < FRAMES - 2; s += 2) {
        STEP(0, s,     1)
        STEP(1, s + 1, 1)
    }
    STEP(0, 510, 1)   // loads+converts frame 511
    STEP(1, 511, 0)   // last step, no load
#undef STEP

    // ---- epilogue: final h (i8, buf0 since FRAMES even) -> f32 ----
    const float dq = 1.f / 127.f;
    float* hout = out + BATCH * OUT_DIM;
    for (int i = tid; i < MT * HIDDEN; i += 512) {
        int r = i / HIDDEN, c = i % HIDDEN;
        hout[(size_t)(b0 + r) * HIDDEN + c] =
            (float)((int)(signed char)ldsb[r * HROW + ((r & 7) << 4) + c]) * dq;
    }
    if (tid < MT * OUT_DIM) {
        int r = tid / OUT_DIM, c = tid % OUT_DIM;
        float sum = 0.f;
        for (int k = 0; k < HIDDEN; ++k) {
            float h = (float)((int)(signed char)ldsb[r * HROW + ((r & 7) << 4) + k]) * dq;
            sum = fmaf(h, Wo[c * HIDDEN + k], sum);
        }
        out[(b0 + r) * OUT_DIM + c] = sum;
    }
}

extern "C" void kernel_launch(void* const* d_in, const int* in_sizes, int n_in,
                              void* d_out, int out_size, void* d_ws, size_t ws_size,
                              hipStream_t stream) {
    const float* x  = (const float*)d_in[0];
    const float* h0 = (const float*)d_in[1];
    const float* Wi = (const float*)d_in[2];
    const float* Wh = (const float*)d_in[3];
    const float* Wo = (const float*)d_in[4];
    float* out = (float*)d_out;
    rnn_kernel<<<dim3(BATCH / MT), dim3(512), 0, stream>>>(x, h0, Wi, Wh, Wo, out);
}

// Round 16
// 452.156 us; speedup vs baseline: 1.2927x; 1.2927x over previous
//
#include <hip/hip_runtime.h>
#include <hip/hip_bf16.h>

#define FRAMES 512
#define BATCH 2048
#define IN_DIM 84
#define HIDDEN 300
#define OUT_DIM 10

#define MT 16            // batch rows per workgroup
#define HROW 512         // bytes per h row (i8 data 0..319, swizzle pad)
#define XOFF 8192        // x region byte offset within a buffer
#define XROW 512         // bytes per x row (bf16 data 168B + swizzle pad)
#define BUFB 16384       // bytes per buffer
#define KFH 5            // i8 h-fragments (K=64 each: k 0..319, 300 real)
#define KFX 3            // bf16 x-fragments (K=32 each: k 0..95, 84 real)
#define NT 3             // tiles per wave: t = wv, wv+8, wv+16
#define XBASE 176        // x-load/commit lanes tid in [176, 512): biases the
                         // commit work onto the 2-tile waves (3-tile waves gate the barrier)

#define L2E2 2.88539008177792681f   // 2*log2(e), folded into Wi and qs

typedef __attribute__((ext_vector_type(8))) short s8v;
typedef __attribute__((ext_vector_type(4))) short s4v;
typedef __attribute__((ext_vector_type(4))) float f4v;
typedef __attribute__((ext_vector_type(4))) int   i4v;

__device__ __forceinline__ short f2b(float x) {
    __hip_bfloat16 h = __float2bfloat16(x);
    return *reinterpret_cast<short*>(&h);
}
__device__ __forceinline__ void lgkm_barrier() {   // no vmcnt drain at barrier
    asm volatile("s_waitcnt lgkmcnt(0)" ::: "memory");
    __builtin_amdgcn_s_barrier();
}

// Swapped-operand step:  pre[n][b] = qs*(i8dot: Wh_q . h_q) + (bf16: (c*Wi) . x)
//   tanh+quant tail fully fused (see TAIL); h' write = ONE ds_write_b32 per tile.
//   x-commit via v_cvt_pk_bf16_f32 (2 instrs for 4 floats, no builtin on gfx950).

#define MFI(T, K, ACC) ACC = __builtin_amdgcn_mfma_i32_16x16x64_i8(wq[T][K], bh[K], ACC, 0, 0, 0)
#define MFX(T, K, ACC) ACC = __builtin_amdgcn_mfma_f32_16x16x32_bf16(wx[T][K], bx[K], ACC, 0, 0, 0)
#define TAIL(AI, AF, IDX) do { unsigned b_[4];                                  \
        _Pragma("unroll")                                                       \
        for (int r_ = 0; r_ < 4; ++r_) {                                        \
            float z2_ = fmaf(qs2885, (float)AI[r_], AF[r_]);                    \
            float ex_ = __builtin_amdgcn_exp2f(z2_);                            \
            b_[r_] = __float_as_uint(                                           \
                fmaf(-254.f, __builtin_amdgcn_rcpf(ex_ + 1.f), 12583039.f));    \
        }                                                                       \
        unsigned t0_ = __builtin_amdgcn_perm(b_[1], b_[0], 0x00000400u);        \
        unsigned t1_ = __builtin_amdgcn_perm(b_[3], b_[2], 0x00000400u);        \
        unsigned pk_ = __builtin_amdgcn_perm(t1_, t0_, 0x05040100u);            \
        *(unsigned*)&ldsb[IDX] = pk_; } while (0)

__global__ __launch_bounds__(512, 2)
void rnn_kernel(const float* __restrict__ x, const float* __restrict__ h0,
                const float* __restrict__ Wi, const float* __restrict__ Wh,
                const float* __restrict__ Wo, float* __restrict__ out)
{
    __shared__ __align__(16) char ldsb[2 * BUFB];
    __shared__ float redbuf[8];
    const int tid  = threadIdx.x;
    const int lane = tid & 63;
    const int wv   = tid >> 6;          // wave 0..7
    const int l15  = lane & 15;
    const int lkhi = lane >> 4;
    const int b0   = blockIdx.x * MT;
    const bool w3  = (wv < 3);

    // ---- deterministic global max|Wh| (identical in every WG) ----
    float m = 0.f;
    for (int i = tid; i < HIDDEN * HIDDEN; i += 512)
        m = fmaxf(m, fabsf(Wh[i]));
#pragma unroll
    for (int o = 32; o; o >>= 1) m = fmaxf(m, __shfl_xor(m, o));
    if (lane == 0) redbuf[wv] = m;
    __syncthreads();
    float gm = 0.f;
#pragma unroll
    for (int i = 0; i < 8; ++i) gm = fmaxf(gm, redbuf[i]);
    const float inv_sw = 127.f / gm;                    // Wh -> q
    const float qs2885 = (gm / (127.f * 127.f)) * L2E2; // dequant * 2log2e fused

    // ---- weight-stationary fragments: i8 Wh + bf16 (L2E2 * Wi) ----
    i4v wq[NT][KFH];
    s8v wx[NT][KFX];
#pragma unroll
    for (int i = 0; i < NT; ++i) {
        const int n = (wv + 8 * i) * 16 + l15;
#pragma unroll
        for (int kf = 0; kf < KFH; ++kf) {
            int dw0 = 0, dw1 = 0, dw2 = 0, dw3 = 0;
#pragma unroll
            for (int j = 0; j < 16; ++j) {
                int k = kf * 64 + lkhi * 16 + j;
                float f = (n < HIDDEN && k < HIDDEN) ? Wh[n * HIDDEN + k] : 0.f;
                int q = (int)rintf(f * inv_sw) & 255;
                if ((j >> 2) == 0) dw0 |= q << ((j & 3) * 8);
                else if ((j >> 2) == 1) dw1 |= q << ((j & 3) * 8);
                else if ((j >> 2) == 2) dw2 |= q << ((j & 3) * 8);
                else dw3 |= q << ((j & 3) * 8);
            }
            wq[i][kf] = (i4v){dw0, dw1, dw2, dw3};
        }
#pragma unroll
        for (int f = 0; f < KFX; ++f) {
            s8v v;
#pragma unroll
            for (int j = 0; j < 8; ++j) {
                int k = f * 32 + lkhi * 8 + j;
                v[j] = f2b((n < HIDDEN && k < IN_DIM) ? L2E2 * Wi[n * IN_DIM + k] : 0.f);
            }
            wx[i][f] = v;
        }
    }

    // ---- zero both buffers (all pads must be 0) ----
    {
        i4v z = (i4v){0, 0, 0, 0};
        for (int i = tid; i < 2 * BUFB / 16; i += 512)
            ((i4v*)ldsb)[i] = z;
    }
    __syncthreads();

    // ---- h0 (quantized) -> buf0, frame-0 x (bf16) -> buf0 ----
    for (int i = tid; i < MT * HIDDEN; i += 512) {
        int r = i / HIDDEN, c = i % HIDDEN;
        float h = h0[(size_t)(b0 + r) * HIDDEN + c];
        ldsb[r * HROW + ((r & 7) << 4) + c] =
            (char)(__float_as_uint(fmaf(h, 127.f, 12582912.f)) & 255u);
    }
    {
        const bool xa0_ = (tid >= XBASE);
        const int  xi0_ = xa0_ ? tid - XBASE : 0;
        if (xa0_) {
            const float4* xs = reinterpret_cast<const float4*>(x + (size_t)b0 * IN_DIM);
            float4 v0 = xs[xi0_];
            int r = xi0_ / 21, c = xi0_ % 21;
            s4v pk = {f2b(v0.x), f2b(v0.y), f2b(v0.z), f2b(v0.w)};
            *reinterpret_cast<s4v*>(&ldsb[XOFF + r * XROW + ((r & 7) << 4) + c * 8]) = pk;
        }
    }

    // ---- per-lane constant byte bases ----
    const int hrd = l15 * HROW + ((l15 & 7) << 4) + lkhi * 16;   // + kf*64
    const int hwr = l15 * HROW + ((l15 & 7) << 4) + lkhi * 4;    // + t*16
    const int xrd = XOFF + l15 * XROW + ((l15 & 7) << 4) + lkhi * 16; // + f*64
    const bool xact = (tid >= XBASE);
    const int  xi   = xact ? tid - XBASE : 0;       // 0..335 on active lanes
    const int  xr_  = xi / 21, xc_ = xi % 21;
    const int  xcb  = XOFF + xr_ * XROW + ((xr_ & 7) << 4) + xc_ * 8;
    const f4v zero4 = (f4v){0.f, 0.f, 0.f, 0.f};
    const i4v zeroi = (i4v){0, 0, 0, 0};

    // frame-1 preload
    float4 xa0, xb0;
    xa0 = reinterpret_cast<const float4*>(x + ((size_t)BATCH + b0) * IN_DIM)[xi];
    __syncthreads();

#define STEP(PH, SF, A0, B0, LOADF, COMMITF)                                    \
    {                                                                           \
        if (LOADF) {                                                            \
            B0 = reinterpret_cast<const float4*>(                               \
                x + ((size_t)((SF) + 2) * BATCH + b0) * IN_DIM)[xi];            \
        }                                                                       \
        if ((COMMITF) && xact) {                                                \
            unsigned d0_, d1_;                                                  \
            asm("v_cvt_pk_bf16_f32 %0, %1, %2" : "=v"(d0_) : "v"(A0.x), "v"(A0.y)); \
            asm("v_cvt_pk_bf16_f32 %0, %1, %2" : "=v"(d1_) : "v"(A0.z), "v"(A0.w)); \
            uint2 pk_; pk_.x = d0_; pk_.y = d1_;                                \
            *(uint2*)&ldsb[((PH) ^ 1) * BUFB + xcb] = pk_;                      \
        }                                                                       \
        i4v bh[KFH]; s8v bx[KFX];                                               \
        _Pragma("unroll")                                                       \
        for (int kf = 0; kf < KFH; ++kf)                                        \
            bh[kf] = *(const i4v*)&ldsb[(PH) * BUFB + hrd + kf * 64];           \
        _Pragma("unroll")                                                       \
        for (int f = 0; f < KFX; ++f)                                           \
            bx[f] = *(const s8v*)&ldsb[(PH) * BUFB + xrd + f * 64];             \
        __builtin_amdgcn_s_setprio(1);                                          \
        if (w3) {                                                               \
            i4v a0i = __builtin_amdgcn_mfma_i32_16x16x64_i8(wq[0][0], bh[0], zeroi, 0, 0, 0); \
            i4v a1i = __builtin_amdgcn_mfma_i32_16x16x64_i8(wq[1][0], bh[0], zeroi, 0, 0, 0); \
            i4v a2i = __builtin_amdgcn_mfma_i32_16x16x64_i8(wq[2][0], bh[0], zeroi, 0, 0, 0); \
            _Pragma("unroll")                                                   \
            for (int kf = 1; kf < KFH; ++kf) {                                  \
                MFI(0, kf, a0i); MFI(1, kf, a1i); MFI(2, kf, a2i);              \
            }                                                                   \
            f4v a0f = __builtin_amdgcn_mfma_f32_16x16x32_bf16(wx[0][0], bx[0], zero4, 0, 0, 0); \
            f4v a1f = __builtin_amdgcn_mfma_f32_16x16x32_bf16(wx[1][0], bx[0], zero4, 0, 0, 0); \
            f4v a2f = __builtin_amdgcn_mfma_f32_16x16x32_bf16(wx[2][0], bx[0], zero4, 0, 0, 0); \
            _Pragma("unroll")                                                   \
            for (int f = 1; f < KFX; ++f) {                                     \
                MFX(0, f, a0f); MFX(1, f, a1f); MFX(2, f, a2f);                 \
            }                                                                   \
            __builtin_amdgcn_s_setprio(0);                                      \
            TAIL(a0i, a0f, ((PH) ^ 1) * BUFB + hwr + (wv) * 16);                \
            TAIL(a1i, a1f, ((PH) ^ 1) * BUFB + hwr + (wv + 8) * 16);            \
            TAIL(a2i, a2f, ((PH) ^ 1) * BUFB + hwr + (wv + 16) * 16);           \
        } else {                                                                \
            i4v a0i = __builtin_amdgcn_mfma_i32_16x16x64_i8(wq[0][0], bh[0], zeroi, 0, 0, 0); \
            i4v a1i = __builtin_amdgcn_mfma_i32_16x16x64_i8(wq[1][0], bh[0], zeroi, 0, 0, 0); \
            _Pragma("unroll")                                                   \
            for (int kf = 1; kf < KFH; ++kf) {                                  \
                MFI(0, kf, a0i); MFI(1, kf, a1i);                               \
            }                                                                   \
            f4v a0f = __builtin_amdgcn_mfma_f32_16x16x32_bf16(wx[0][0], bx[0], zero4, 0, 0, 0); \
            f4v a1f = __builtin_amdgcn_mfma_f32_16x16x32_bf16(wx[1][0], bx[0], zero4, 0, 0, 0); \
            _Pragma("unroll")                                                   \
            for (int f = 1; f < KFX; ++f) {                                     \
                MFX(0, f, a0f); MFX(1, f, a1f);                                 \
            }                                                                   \
            __builtin_amdgcn_s_setprio(0);                                      \
            TAIL(a0i, a0f, ((PH) ^ 1) * BUFB + hwr + (wv) * 16);                \
            TAIL(a1i, a1f, ((PH) ^ 1) * BUFB + hwr + (wv + 8) * 16);            \
        }                                                                       \
        lgkm_barrier();                                                         \
    }

    for (int s = 0; s < FRAMES - 2; s += 2) {
        STEP(0, s,     xa0, xb0, 1, 1)
        STEP(1, s + 1, xb0, xa0, 1, 1)
    }
    STEP(0, 510, xa0, xb0, 0, 1)
    STEP(1, 511, xb0, xa0, 0, 0)
#undef STEP

    // ---- epilogue: final h (i8, buf0 since FRAMES even) -> f32 ----
    const float dq = 1.f / 127.f;
    float* hout = out + BATCH * OUT_DIM;
    for (int i = tid; i < MT * HIDDEN; i += 512) {
        int r = i / HIDDEN, c = i % HIDDEN;
        hout[(size_t)(b0 + r) * HIDDEN + c] =
            (float)((int)(signed char)ldsb[r * HROW + ((r & 7) << 4) + c]) * dq;
    }
    if (tid < MT * OUT_DIM) {
        int r = tid / OUT_DIM, c = tid % OUT_DIM;
        float sum = 0.f;
        for (int k = 0; k < HIDDEN; ++k) {
            float h = (float)((int)(signed char)ldsb[r * HROW + ((r & 7) << 4) + k]) * dq;
            sum = fmaf(h, Wo[c * HIDDEN + k], sum);
        }
        out[(b0 + r) * OUT_DIM + c] = sum;
    }
}

extern "C" void kernel_launch(void* const* d_in, const int* in_sizes, int n_in,
                              void* d_out, int out_size, void* d_ws, size_t ws_size,
                              hipStream_t stream) {
    const float* x  = (const float*)d_in[0];
    const float* h0 = (const float*)d_in[1];
    const float* Wi = (const float*)d_in[2];
    const float* Wh = (const float*)d_in[3];
    const float* Wo = (const float*)d_in[4];
    float* out = (float*)d_out;
    rnn_kernel<<<dim3(BATCH / MT), dim3(512), 0, stream>>>(x, h0, Wi, Wh, Wo, out);
}